// Round 7
// baseline (18286.781 us; speedup 1.0000x reference)
//
#include <hip/hip_runtime.h>

// Only the temporal (LSTM) branch of the reference reaches the output
// (h_gcn is dead). Per node:
//   xt_s = x[n, 52+s] * W_tp + b_tp          (rank-1, folded into A0/C0)
//   2-layer LSTM (H=32, T=12, torch gate order i,f,g,o)
//   out[n] = relu(h1 @ W_fc1 + b_fc1) @ W_fc2 + b_fc2
//
// v5: quad k-split. 4 lanes per node (16 nodes/wave); lane s owns k-slice
// [8s,8s+8) of h0/h1/c0/c1 -> per-lane state 40 floats, NO per-thread LDS.
// Per gate-row j: 8-wide partial dot per lane, quad butterfly
// (__shfl_xor 1,2) completes the sum, owner lane (s==j>>3) updates c and
// stages new-h (already in slice layout for next step). Weights (48 KB)
// staged once in LDS, read as ds_read_b128 off one loop-invariant vaddr +
// immediate offsets (conflict-free, 16-lane broadcast). Grid parallelism
// 4x v1 (6250 waves) -> real TLP; K$ holds only pre[] (no weight stream).
// Lessons kept: no __launch_bounds__ min-waves floor (v2/v3 spill
// disasters); j-split alone doesn't shrink operand state (v4).
// (2nd resubmission: rounds 5 and 6 both failed on GPU acquisition.)

#define TSTEPS 12
#define BS 512               // 8 waves per block
#define NPB (BS / 4)         // 128 nodes per block

__device__ __forceinline__ float fsig(float x) {
    float e = __expf(-x);                      // v_exp path; e in [0, inf)
    return __builtin_amdgcn_rcpf(1.0f + e);    // 1/(1+e), ~1 ulp
}

__device__ __forceinline__ float ftanh(float x) {
    float ax = fabsf(x);
    float e = __expf(-2.0f * ax);              // in (0,1], no overflow
    float r = (1.0f - e) * __builtin_amdgcn_rcpf(1.0f + e);
    return x < 0.0f ? -r : r;
}

// Fold layer-0 input matmul:
//   A0[r] = dot(Wih0[r,:], W_tp)          (scalar per gate row)
//   C0[r] = dot(Wih0[r,:], b_tp) + bih0[r] + bhh0[r]
//   C1[r] = bih1[r] + bhh1[r]
// ws layout: [0:128) A0, [128:256) C0, [256:384) C1
__global__ void precomp_kernel(const float* __restrict__ Wih0,
                               const float* __restrict__ Wtp,
                               const float* __restrict__ btp,
                               const float* __restrict__ bih0,
                               const float* __restrict__ bhh0,
                               const float* __restrict__ bih1,
                               const float* __restrict__ bhh1,
                               float* __restrict__ ws) {
    int r = threadIdx.x;   // 0..127
    if (r < 128) {
        float a = 0.0f, c = 0.0f;
#pragma unroll
        for (int k = 0; k < 16; ++k) {
            float w = Wih0[r * 16 + k];
            a += w * Wtp[k];
            c += w * btp[k];
        }
        ws[r]       = a;
        ws[128 + r] = c + bih0[r] + bhh0[r];
        ws[256 + r] = bih1[r] + bhh1[r];
    }
}

__global__ __launch_bounds__(BS) void lstm_kernel(
    const float* __restrict__ x,
    const float* __restrict__ Whh0,   // [128,32]
    const float* __restrict__ Wih1,   // [128,32]
    const float* __restrict__ Whh1,   // [128,32]
    const float* __restrict__ Wfc1,   // [32,16]
    const float* __restrict__ bfc1,   // [16]
    const float* __restrict__ Wfc2,   // [16]
    const float* __restrict__ bfc2,   // [1]
    const float* __restrict__ pre,    // [384] from precomp
    float* __restrict__ out, int N)
{
    // 48 KB weights: [0:4096) Whh0, [4096:8192) Wih1, [8192:12288) Whh1,
    // all row-major [128][32]. All ds_read offsets < 49152 -> fit the
    // 16-bit immediate; one VGPR base (sW + s*32B) serves every read.
    __shared__ __align__(16) float sW[12288];

    const int tid = threadIdx.x;
#pragma unroll
    for (int i = 0; i < 8; ++i) sW[i * BS + tid]        = Whh0[i * BS + tid];
#pragma unroll
    for (int i = 0; i < 8; ++i) sW[4096 + i * BS + tid] = Wih1[i * BS + tid];
#pragma unroll
    for (int i = 0; i < 8; ++i) sW[8192 + i * BS + tid] = Whh1[i * BS + tid];
    __syncthreads();                    // only barrier in the kernel

    const int s    = tid & 3;           // k-slice 0..3
    const int node = tid >> 2;          // 0..127 within block
    const int so8  = s * 8;             // slice base (floats)
    const int n  = blockIdx.x * NPB + node;
    const int nn = (n < N) ? n : (N > 0 ? N - 1 : 0);
    const float* xr = x + (size_t)nn * 64 + 52;   // last 12 features

    // Per-lane slices: h0/h1/c0/c1 for k,j in [8s, 8s+8).
    float h0r[8], h1r[8], c0r[8], c1r[8];
#pragma unroll
    for (int k = 0; k < 8; ++k) { h0r[k] = 0.0f; h1r[k] = 0.0f; c0r[k] = 0.0f; c1r[k] = 0.0f; }

#pragma unroll 1
    for (int t = 0; t < TSTEPS; ++t) {
        const float xval = xr[t];
        float hn[8];                    // staged new-h (owner slice)
#pragma unroll
        for (int k = 0; k < 8; ++k) hn[k] = 0.0f;

        // ---------------- layer 0 ----------------
#pragma unroll
        for (int g = 0; g < 4; ++g) {
            const bool own = (s == g);
#pragma unroll
            for (int jj = 0; jj < 8; ++jj) {
                const int j = g * 8 + jj;
                const float* wi = &sW[(j      ) * 32 + so8];
                const float* wf = &sW[(j +  32) * 32 + so8];
                const float* wg = &sW[(j +  64) * 32 + so8];
                const float* wo = &sW[(j +  96) * 32 + so8];
                float4 i0 = ((const float4*)wi)[0], i1 = ((const float4*)wi)[1];
                float4 f0 = ((const float4*)wf)[0], f1 = ((const float4*)wf)[1];
                float4 g0 = ((const float4*)wg)[0], g1 = ((const float4*)wg)[1];
                float4 o0 = ((const float4*)wo)[0], o1 = ((const float4*)wo)[1];
                float pi = i0.x*h0r[0] + i0.y*h0r[1] + i0.z*h0r[2] + i0.w*h0r[3]
                         + i1.x*h0r[4] + i1.y*h0r[5] + i1.z*h0r[6] + i1.w*h0r[7];
                float pf = f0.x*h0r[0] + f0.y*h0r[1] + f0.z*h0r[2] + f0.w*h0r[3]
                         + f1.x*h0r[4] + f1.y*h0r[5] + f1.z*h0r[6] + f1.w*h0r[7];
                float pg = g0.x*h0r[0] + g0.y*h0r[1] + g0.z*h0r[2] + g0.w*h0r[3]
                         + g1.x*h0r[4] + g1.y*h0r[5] + g1.z*h0r[6] + g1.w*h0r[7];
                float po = o0.x*h0r[0] + o0.y*h0r[1] + o0.z*h0r[2] + o0.w*h0r[3]
                         + o1.x*h0r[4] + o1.y*h0r[5] + o1.z*h0r[6] + o1.w*h0r[7];
                // quad reduce (stays within the node's 4 lanes)
                pi += __shfl_xor(pi, 1); pi += __shfl_xor(pi, 2);
                pf += __shfl_xor(pf, 1); pf += __shfl_xor(pf, 2);
                pg += __shfl_xor(pg, 1); pg += __shfl_xor(pg, 2);
                po += __shfl_xor(po, 1); po += __shfl_xor(po, 2);
                const float gi = pi + pre[128 + j] + xval * pre[j];
                const float gf = pf + pre[160 + j] + xval * pre[32 + j];
                const float gg = pg + pre[192 + j] + xval * pre[64 + j];
                const float go = po + pre[224 + j] + xval * pre[96 + j];
                // non-owners compute garbage cc/hh (stale c) and discard
                const float cc = fsig(gf) * c0r[jj] + fsig(gi) * ftanh(gg);
                const float hh = fsig(go) * ftanh(cc);
                if (own) { c0r[jj] = cc; hn[jj] = hh; }
            }
        }
#pragma unroll
        for (int k = 0; k < 8; ++k) h0r[k] = hn[k];   // commit new h0

        // ---------------- layer 1 ----------------
#pragma unroll
        for (int g = 0; g < 4; ++g) {
            const bool own = (s == g);
#pragma unroll
            for (int jj = 0; jj < 8; ++jj) {
                const int j = g * 8 + jj;
                const float* ai = &sW[4096 + (j      ) * 32 + so8];
                const float* af = &sW[4096 + (j +  32) * 32 + so8];
                const float* ag = &sW[4096 + (j +  64) * 32 + so8];
                const float* ao = &sW[4096 + (j +  96) * 32 + so8];
                const float* bi = &sW[8192 + (j      ) * 32 + so8];
                const float* bf = &sW[8192 + (j +  32) * 32 + so8];
                const float* bg = &sW[8192 + (j +  64) * 32 + so8];
                const float* bo = &sW[8192 + (j +  96) * 32 + so8];
                float4 u0, u1, v0, v1;
                u0 = ((const float4*)ai)[0]; u1 = ((const float4*)ai)[1];
                v0 = ((const float4*)bi)[0]; v1 = ((const float4*)bi)[1];
                float pi = u0.x*h0r[0] + u0.y*h0r[1] + u0.z*h0r[2] + u0.w*h0r[3]
                         + u1.x*h0r[4] + u1.y*h0r[5] + u1.z*h0r[6] + u1.w*h0r[7]
                         + v0.x*h1r[0] + v0.y*h1r[1] + v0.z*h1r[2] + v0.w*h1r[3]
                         + v1.x*h1r[4] + v1.y*h1r[5] + v1.z*h1r[6] + v1.w*h1r[7];
                u0 = ((const float4*)af)[0]; u1 = ((const float4*)af)[1];
                v0 = ((const float4*)bf)[0]; v1 = ((const float4*)bf)[1];
                float pf = u0.x*h0r[0] + u0.y*h0r[1] + u0.z*h0r[2] + u0.w*h0r[3]
                         + u1.x*h0r[4] + u1.y*h0r[5] + u1.z*h0r[6] + u1.w*h0r[7]
                         + v0.x*h1r[0] + v0.y*h1r[1] + v0.z*h1r[2] + v0.w*h1r[3]
                         + v1.x*h1r[4] + v1.y*h1r[5] + v1.z*h1r[6] + v1.w*h1r[7];
                u0 = ((const float4*)ag)[0]; u1 = ((const float4*)ag)[1];
                v0 = ((const float4*)bg)[0]; v1 = ((const float4*)bg)[1];
                float pg = u0.x*h0r[0] + u0.y*h0r[1] + u0.z*h0r[2] + u0.w*h0r[3]
                         + u1.x*h0r[4] + u1.y*h0r[5] + u1.z*h0r[6] + u1.w*h0r[7]
                         + v0.x*h1r[0] + v0.y*h1r[1] + v0.z*h1r[2] + v0.w*h1r[3]
                         + v1.x*h1r[4] + v1.y*h1r[5] + v1.z*h1r[6] + v1.w*h1r[7];
                u0 = ((const float4*)ao)[0]; u1 = ((const float4*)ao)[1];
                v0 = ((const float4*)bo)[0]; v1 = ((const float4*)bo)[1];
                float po = u0.x*h0r[0] + u0.y*h0r[1] + u0.z*h0r[2] + u0.w*h0r[3]
                         + u1.x*h0r[4] + u1.y*h0r[5] + u1.z*h0r[6] + u1.w*h0r[7]
                         + v0.x*h1r[0] + v0.y*h1r[1] + v0.z*h1r[2] + v0.w*h1r[3]
                         + v1.x*h1r[4] + v1.y*h1r[5] + v1.z*h1r[6] + v1.w*h1r[7];
                pi += __shfl_xor(pi, 1); pi += __shfl_xor(pi, 2);
                pf += __shfl_xor(pf, 1); pf += __shfl_xor(pf, 2);
                pg += __shfl_xor(pg, 1); pg += __shfl_xor(pg, 2);
                po += __shfl_xor(po, 1); po += __shfl_xor(po, 2);
                const float gi = pi + pre[256 + j];
                const float gf = pf + pre[288 + j];
                const float gg = pg + pre[320 + j];
                const float go = po + pre[352 + j];
                const float cc = fsig(gf) * c1r[jj] + fsig(gi) * ftanh(gg);
                const float hh = fsig(go) * ftanh(cc);
                if (own) { c1r[jj] = cc; hn[jj] = hh; }
            }
        }
#pragma unroll
        for (int k = 0; k < 8; ++k) h1r[k] = hn[k];   // commit new h1
    }

    // epilogue: relu(h1 @ Wfc1 + bfc1) @ Wfc2 + bfc2 (h1 sliced over quad)
    float am[16];
#pragma unroll
    for (int m = 0; m < 16; ++m) am[m] = 0.0f;
#pragma unroll
    for (int kk = 0; kk < 8; ++kk) {
        const float* row = Wfc1 + (size_t)(so8 + kk) * 16;
        const float4 r0 = ((const float4*)row)[0];
        const float4 r1 = ((const float4*)row)[1];
        const float4 r2 = ((const float4*)row)[2];
        const float4 r3 = ((const float4*)row)[3];
        const float hv = h1r[kk];
        am[ 0] += r0.x*hv; am[ 1] += r0.y*hv; am[ 2] += r0.z*hv; am[ 3] += r0.w*hv;
        am[ 4] += r1.x*hv; am[ 5] += r1.y*hv; am[ 6] += r1.z*hv; am[ 7] += r1.w*hv;
        am[ 8] += r2.x*hv; am[ 9] += r2.y*hv; am[10] += r2.z*hv; am[11] += r2.w*hv;
        am[12] += r3.x*hv; am[13] += r3.y*hv; am[14] += r3.z*hv; am[15] += r3.w*hv;
    }
    float acc = bfc2[0];
#pragma unroll
    for (int m = 0; m < 16; ++m) {
        float a = am[m];
        a += __shfl_xor(a, 1); a += __shfl_xor(a, 2);
        acc += fmaxf(a + bfc1[m], 0.0f) * Wfc2[m];
    }
    if (s == 0 && n < N) out[n] = acc;
}

extern "C" void kernel_launch(void* const* d_in, const int* in_sizes, int n_in,
                              void* d_out, int out_size, void* d_ws, size_t ws_size,
                              hipStream_t stream) {
    (void)n_in; (void)out_size; (void)ws_size;
    // setup_inputs() order:
    // 0 x, 1 edge_index, 2 W_fp, 3 b_fp, 4 W_g1, 5 b_g1, 6 W_g2, 7 b_g2,
    // 8 W_g3, 9 b_g3, 10 W_tp, 11 b_tp, 12 Wih0, 13 Whh0, 14 bih0, 15 bhh0,
    // 16 Wih1, 17 Whh1, 18 bih1, 19 bhh1, 20 W_fc1, 21 b_fc1, 22 W_fc2, 23 b_fc2
    const float* x    = (const float*)d_in[0];
    const float* Wtp  = (const float*)d_in[10];
    const float* btp  = (const float*)d_in[11];
    const float* Wih0 = (const float*)d_in[12];
    const float* Whh0 = (const float*)d_in[13];
    const float* bih0 = (const float*)d_in[14];
    const float* bhh0 = (const float*)d_in[15];
    const float* Wih1 = (const float*)d_in[16];
    const float* Whh1 = (const float*)d_in[17];
    const float* bih1 = (const float*)d_in[18];
    const float* bhh1 = (const float*)d_in[19];
    const float* Wfc1 = (const float*)d_in[20];
    const float* bfc1 = (const float*)d_in[21];
    const float* Wfc2 = (const float*)d_in[22];
    const float* bfc2 = (const float*)d_in[23];

    float* out = (float*)d_out;
    float* pre = (float*)d_ws;   // 384 floats

    const int N = in_sizes[0] / 64;

    precomp_kernel<<<1, 128, 0, stream>>>(Wih0, Wtp, btp, bih0, bhh0, bih1, bhh1, pre);
    lstm_kernel<<<(N + NPB - 1) / NPB, BS, 0, stream>>>(
        x, Whh0, Wih1, Whh1, Wfc1, bfc1, Wfc2, bfc2, pre, out, N);
}

// Round 10
// 1975.544 us; speedup vs baseline: 9.2566x; 9.2566x over previous
//
#include <hip/hip_runtime.h>

// Only the temporal (LSTM) branch of the reference reaches the output
// (h_gcn is dead). Per node:
//   xt_s = x[n, 52+s] * W_tp + b_tp          (rank-1, folded into A0/C0)
//   2-layer LSTM (H=32, T=12, torch gate order i,f,g,o)
//   out[n] = relu(h1 @ W_fc1 + b_fc1) @ W_fc2 + b_fc2
//
// v6 = v4 (4 waves cooperate on 64 nodes, j-split across waves) with the
// register-allocator defect fixed: __launch_bounds__(BS, 1).
//   - v4 (plain __launch_bounds__(256)) made the allocator target high
//     occupancy -> VGPR_Count=60 -> h0/h1 re-read from LDS every FMA ->
//     2.7x instruction stream (VALUBusy 82% but 1941 us).
//   - (BS,1) raises the VGPR ceiling (cannot force a spill, unlike v2's
//     (256,4) -> 64-reg disaster); allocator register-caches h like v1's
//     104-VGPR allocation.
// Structure: wave w computes gate rows j in [8w,8w+8). h-state replicated
// in registers (static indices); c-state partitioned in LDS columns
// (owner-only); new-h double-buffered in LDS (snhA/snhB), one barrier per
// layer. Weights via SGPR-uniform s_load (jbase pinned by readfirstlane).
// Expect VGPR ~110 -> 4 waves/SIMD; LDS 32KB -> 4 blocks/CU = 16 waves/CU.
// (2nd resubmission: rounds 8 and 9 both failed on GPU acquisition.)

#define TSTEPS 12
#define NPB 64               // nodes per block
#define NW 4                 // waves per block
#define BS (NPB * NW)        // 256 threads
#define NJ (32 / NW)         // 8 gate-rows per wave

__device__ __forceinline__ float fsig(float x) {
    float e = __expf(-x);                      // v_exp path; e in [0, inf)
    return __builtin_amdgcn_rcpf(1.0f + e);    // 1/(1+e), ~1 ulp
}

__device__ __forceinline__ float ftanh(float x) {
    float ax = fabsf(x);
    float e = __expf(-2.0f * ax);              // in (0,1], no overflow
    float r = (1.0f - e) * __builtin_amdgcn_rcpf(1.0f + e);
    return x < 0.0f ? -r : r;
}

// Fold layer-0 input matmul:
//   A0[r] = dot(Wih0[r,:], W_tp)          (scalar per gate row)
//   C0[r] = dot(Wih0[r,:], b_tp) + bih0[r] + bhh0[r]
//   C1[r] = bih1[r] + bhh1[r]
// ws layout: [0:128) A0, [128:256) C0, [256:384) C1
__global__ void precomp_kernel(const float* __restrict__ Wih0,
                               const float* __restrict__ Wtp,
                               const float* __restrict__ btp,
                               const float* __restrict__ bih0,
                               const float* __restrict__ bhh0,
                               const float* __restrict__ bih1,
                               const float* __restrict__ bhh1,
                               float* __restrict__ ws) {
    int r = threadIdx.x;   // 0..127
    if (r < 128) {
        float a = 0.0f, c = 0.0f;
#pragma unroll
        for (int k = 0; k < 16; ++k) {
            float w = Wih0[r * 16 + k];
            a += w * Wtp[k];
            c += w * btp[k];
        }
        ws[r]       = a;
        ws[128 + r] = c + bih0[r] + bhh0[r];
        ws[256 + r] = bih1[r] + bhh1[r];
    }
}

__global__ __launch_bounds__(BS, 1) void lstm_kernel(
    const float* __restrict__ x,
    const float* __restrict__ Whh0,   // [128,32]
    const float* __restrict__ Wih1,   // [128,32]
    const float* __restrict__ Whh1,   // [128,32]
    const float* __restrict__ Wfc1,   // [32,16]
    const float* __restrict__ bfc1,   // [16]
    const float* __restrict__ Wfc2,   // [16]
    const float* __restrict__ bfc2,   // [1]
    const float* __restrict__ pre,    // [384] from precomp
    float* __restrict__ out, int N)
{
    // c-state: partitioned, each wave owns its j-range columns (owner-only
    // access, no sync). snhA/snhB: h staged by producers, read by ALL
    // threads. Index [j*NPB + node]: consecutive lanes -> consecutive
    // banks (2 lanes/bank for wave64 = free).
    __shared__ float sc0 [32 * NPB];
    __shared__ float sc1 [32 * NPB];
    __shared__ float snhA[32 * NPB];   // layer-0 new h
    __shared__ float snhB[32 * NPB];   // layer-1 new h

    const int tid  = threadIdx.x;
    const int node = tid & (NPB - 1);
    // Wave-uniform gate-row base, FORCED into an SGPR so weight addresses
    // take the scalar-load (K$) path instead of per-lane vector loads.
    const int jbase = __builtin_amdgcn_readfirstlane((tid >> 6) * NJ);
    const int n  = blockIdx.x * NPB + node;
    const int nn = (n < N) ? n : (N > 0 ? N - 1 : 0);
    const float* xr = x + (size_t)nn * 64 + 52;   // last 12 features

    float h0[32], h1[32];
#pragma unroll
    for (int k = 0; k < 32; ++k) { h0[k] = 0.0f; h1[k] = 0.0f; }
#pragma unroll
    for (int jj = 0; jj < NJ; ++jj) {             // owner-only init, no sync
        sc0[(jbase + jj) * NPB + node] = 0.0f;
        sc1[(jbase + jj) * NPB + node] = 0.0f;
    }

#pragma unroll 1
    for (int t = 0; t < TSTEPS; ++t) {
        const float xval = xr[t];

        // ---------------- layer 0 (this wave's 8 gate rows) -------------
#pragma unroll 1
        for (int jj = 0; jj < NJ; ++jj) {
            const int j = jbase + jj;             // SGPR-resident
            float gi = pre[128 + j] + xval * pre[j];
            float gf = pre[160 + j] + xval * pre[32 + j];
            float gg = pre[192 + j] + xval * pre[64 + j];
            float go = pre[224 + j] + xval * pre[96 + j];
            const float* w = Whh0 + j * 32;       // rows j, j+32, j+64, j+96
#pragma unroll
            for (int k = 0; k < 32; ++k) {
                const float hk = h0[k];
                gi += w[k]        * hk;
                gf += w[1024 + k] * hk;
                gg += w[2048 + k] * hk;
                go += w[3072 + k] * hk;
            }
            const int ci = j * NPB + node;
            const float cc = fsig(gf) * sc0[ci] + fsig(gi) * ftanh(gg);
            sc0[ci]  = cc;
            snhA[ci] = fsig(go) * ftanh(cc);
        }
        __syncthreads();                           // snhA complete
#pragma unroll
        for (int k = 0; k < 32; ++k) h0[k] = snhA[k * NPB + node];

        // ---------------- layer 1 (this wave's 8 gate rows) -------------
#pragma unroll 1
        for (int jj = 0; jj < NJ; ++jj) {
            const int j = jbase + jj;
            float gi = pre[256 + j];
            float gf = pre[288 + j];
            float gg = pre[320 + j];
            float go = pre[352 + j];
            const float* wi = Wih1 + j * 32;
            const float* wh = Whh1 + j * 32;
#pragma unroll
            for (int k = 0; k < 32; ++k) {
                const float ak = h0[k];
                const float bk = h1[k];
                gi += wi[k]        * ak + wh[k]        * bk;
                gf += wi[1024 + k] * ak + wh[1024 + k] * bk;
                gg += wi[2048 + k] * ak + wh[2048 + k] * bk;
                go += wi[3072 + k] * ak + wh[3072 + k] * bk;
            }
            const int ci = j * NPB + node;
            const float cc = fsig(gf) * sc1[ci] + fsig(gi) * ftanh(gg);
            sc1[ci]  = cc;
            snhB[ci] = fsig(go) * ftanh(cc);
        }
        __syncthreads();                           // snhB complete; also
                                                   // fences snhA reads vs
                                                   // next-t layer-0 writes
#pragma unroll
        for (int k = 0; k < 32; ++k) h1[k] = snhB[k * NPB + node];
        // snhB reads vs next-t layer-1 writes are fenced by the next
        // iteration's first barrier.
    }

    // epilogue: relu(h1 @ Wfc1 + bfc1) @ Wfc2 + bfc2 — wave 0 only
    // (h1 is replicated in every thread's registers)
    if (tid < NPB) {
        float acc = bfc2[0];
#pragma unroll 1
        for (int m = 0; m < 16; ++m) {
            float a = bfc1[m];
#pragma unroll
            for (int k = 0; k < 32; ++k) a += h1[k] * Wfc1[k * 16 + m];
            acc += fmaxf(a, 0.0f) * Wfc2[m];
        }
        if (n < N) out[n] = acc;
    }
}

extern "C" void kernel_launch(void* const* d_in, const int* in_sizes, int n_in,
                              void* d_out, int out_size, void* d_ws, size_t ws_size,
                              hipStream_t stream) {
    (void)n_in; (void)out_size; (void)ws_size;
    // setup_inputs() order:
    // 0 x, 1 edge_index, 2 W_fp, 3 b_fp, 4 W_g1, 5 b_g1, 6 W_g2, 7 b_g2,
    // 8 W_g3, 9 b_g3, 10 W_tp, 11 b_tp, 12 Wih0, 13 Whh0, 14 bih0, 15 bhh0,
    // 16 Wih1, 17 Whh1, 18 bih1, 19 bhh1, 20 W_fc1, 21 b_fc1, 22 W_fc2, 23 b_fc2
    const float* x    = (const float*)d_in[0];
    const float* Wtp  = (const float*)d_in[10];
    const float* btp  = (const float*)d_in[11];
    const float* Wih0 = (const float*)d_in[12];
    const float* Whh0 = (const float*)d_in[13];
    const float* bih0 = (const float*)d_in[14];
    const float* bhh0 = (const float*)d_in[15];
    const float* Wih1 = (const float*)d_in[16];
    const float* Whh1 = (const float*)d_in[17];
    const float* bih1 = (const float*)d_in[18];
    const float* bhh1 = (const float*)d_in[19];
    const float* Wfc1 = (const float*)d_in[20];
    const float* bfc1 = (const float*)d_in[21];
    const float* Wfc2 = (const float*)d_in[22];
    const float* bfc2 = (const float*)d_in[23];

    float* out = (float*)d_out;
    float* pre = (float*)d_ws;   // 384 floats

    const int N = in_sizes[0] / 64;

    precomp_kernel<<<1, 128, 0, stream>>>(Wih0, Wtp, btp, bih0, bhh0, bih1, bhh1, pre);
    lstm_kernel<<<(N + NPB - 1) / NPB, BS, 0, stream>>>(
        x, Whh0, Wih1, Whh1, Wfc1, bfc1, Wfc2, bfc2, pre, out, N);
}